// Round 1
// baseline (317.716 us; speedup 1.0000x reference)
//
#include <hip/hip_runtime.h>
#include <math.h>

#define BSAMP 4096
#define D_IN  768
#define D_OUT 1024
#define NEXP  10
#define LN_EPS 1e-5f
#define KT1 (D_IN / 32)    // 24
#define KT2 (D_OUT / 32)   // 32

typedef __attribute__((ext_vector_type(8))) short bf16x8;
typedef __attribute__((ext_vector_type(4))) float f32x4;

__device__ __forceinline__ float b2f(unsigned short u) {
    union { unsigned int i; float f; } v; v.i = ((unsigned int)u) << 16; return v.f;
}
__device__ __forceinline__ unsigned short f2b(float f) {
    union { float f; unsigned int i; } v; v.f = f;
    unsigned int x = v.i;
    unsigned int r = (x + 0x7fffu + ((x >> 16) & 1u)) >> 16;   // RNE
    return (unsigned short)r;
}

// ---------------- routing ----------------

__global__ void k4_init(int* counts, int* cursor) {
    int t = threadIdx.x;
    if (t < 16) { counts[t] = 0; cursor[t] = 0; }
}

__global__ void k4_router(const float* __restrict__ logits,
                          int* __restrict__ cls, int* __restrict__ counts,
                          float* __restrict__ out1) {
    int b = blockIdx.x * 256 + threadIdx.x;
    if (b >= BSAMP) return;
    const float* L = logits + (size_t)b * NEXP;
    float best = L[0]; int be = 0;
    #pragma unroll
    for (int e = 0; e < NEXP; e++) {
        float v = L[e];
        out1[(size_t)b * NEXP + e] = v;          // f32 bit-exact passthrough
        if (v > best) { best = v; be = e; }      // strict > == first-max (jnp.argmax)
    }
    cls[b] = be;
    atomicAdd(&counts[be], 1);
}

__global__ void k4_scan(const int* counts, int* offs, int* cursor) {
    if (threadIdx.x == 0) {
        int s = 0;
        for (int e = 0; e < NEXP; e++) { offs[e] = s; cursor[e] = s; s += counts[e]; }
        offs[NEXP] = s;
    }
}

__global__ void k4_scatter(const int* __restrict__ cls, int* __restrict__ cursor,
                           int* __restrict__ idx) {
    int b = blockIdx.x * 256 + threadIdx.x;
    if (b >= BSAMP) return;
    int p = atomicAdd(&cursor[cls[b]], 1);
    idx[p] = b;
}

// ---------------- x: f32 -> bf16, flat ----------------
__global__ __launch_bounds__(256)
void k5_xcvt(const float* __restrict__ X, unsigned short* __restrict__ xb) {
    int i = (blockIdx.x * 256 + threadIdx.x) * 8;
    float4 v0 = *(const float4*)(X + i);
    float4 v1 = *(const float4*)(X + i + 4);
    unsigned short t[8] = { f2b(v0.x), f2b(v0.y), f2b(v0.z), f2b(v0.w),
                            f2b(v1.x), f2b(v1.y), f2b(v1.z), f2b(v1.w) };
    *(bf16x8*)(xb + i) = *(bf16x8*)t;
}

// ---------------- weight convert+transpose: W[e][k][n] f32 -> tiled bf16 ----------------
// Wt tile layout: [e][nt(=n>>7)][kt(=k>>5)][nn(128)][kk(32)], tile = 4096 elems = 8 KB.
__global__ __launch_bounds__(256)
void k4_cvt(const float* __restrict__ W, unsigned short* __restrict__ Wt, int K) {
    const int t  = threadIdx.x;
    const int kt = blockIdx.x;          // K/32
    const int e  = blockIdx.z;
    const int n  = blockIdx.y * 256 + t;
    const int KT = K >> 5;
    const float* src = W + ((size_t)e * K + (size_t)kt * 32) * D_OUT + n;
    unsigned short v[32];
    #pragma unroll
    for (int j = 0; j < 32; j++) v[j] = f2b(src[(size_t)j * D_OUT]);
    const int nt = n >> 7, nn = n & 127;
    unsigned short* dst = Wt + ((((size_t)e * 8 + nt) * KT + kt) << 12) + nn * 32;
    #pragma unroll
    for (int j = 0; j < 4; j++)
        *(bf16x8*)&dst[j * 8] = *(bf16x8*)&v[j * 8];
}

// 8 MFMA on one K-step: 2 row-fragments x 4 col-fragments
#define MM8(a0v, a1v, bbuf) \
    acc[0][0] = __builtin_amdgcn_mfma_f32_16x16x32_bf16(a0v, bbuf[0], acc[0][0], 0, 0, 0); \
    acc[0][1] = __builtin_amdgcn_mfma_f32_16x16x32_bf16(a0v, bbuf[1], acc[0][1], 0, 0, 0); \
    acc[0][2] = __builtin_amdgcn_mfma_f32_16x16x32_bf16(a0v, bbuf[2], acc[0][2], 0, 0, 0); \
    acc[0][3] = __builtin_amdgcn_mfma_f32_16x16x32_bf16(a0v, bbuf[3], acc[0][3], 0, 0, 0); \
    acc[1][0] = __builtin_amdgcn_mfma_f32_16x16x32_bf16(a1v, bbuf[0], acc[1][0], 0, 0, 0); \
    acc[1][1] = __builtin_amdgcn_mfma_f32_16x16x32_bf16(a1v, bbuf[1], acc[1][1], 0, 0, 0); \
    acc[1][2] = __builtin_amdgcn_mfma_f32_16x16x32_bf16(a1v, bbuf[2], acc[1][2], 0, 0, 0); \
    acc[1][3] = __builtin_amdgcn_mfma_f32_16x16x32_bf16(a1v, bbuf[3], acc[1][3], 0, 0, 0);

// ---------------- GEMM1: e1g/g1g[p][n] from xb[idx[p]] @ W1[e], LDS-free ----------------
// 64x128 tile, 4 waves (2x2), fragments loaded straight from global, 1-step prefetch.
__global__ __launch_bounds__(256)
void k5_gemm1(const unsigned short* __restrict__ xb, const unsigned short* __restrict__ W1t,
              const int* __restrict__ offs, const int* __restrict__ idx,
              unsigned short* __restrict__ e1g, unsigned short* __restrict__ g1g) {
    const int e = blockIdx.z;
    const int rowStart = offs[e] + blockIdx.y * 64;
    const int rowEnd = offs[e + 1];
    if (rowStart >= rowEnd) return;
    const int nt = blockIdx.x;

    const int tid  = threadIdx.x;
    const int lane = tid & 63;
    const int wave = tid >> 6;
    const int quad = lane >> 4;
    const int l16  = lane & 15;
    const int wrow = (wave & 1) * 32;
    const int wcol = (wave >> 1) * 64;

    int p0 = rowStart + wrow + l16;
    int p1 = p0 + 16;
    const unsigned short* aPtr0 = xb + (size_t)idx[p0 < rowEnd ? p0 : rowEnd - 1] * D_IN + quad * 8;
    const unsigned short* aPtr1 = xb + (size_t)idx[p1 < rowEnd ? p1 : rowEnd - 1] * D_IN + quad * 8;
    const unsigned short* bBase = W1t + ((((size_t)e * 8 + nt) * KT1) << 12) + (wcol + l16) * 32 + quad * 8;

    f32x4 acc[2][4];
    const f32x4 zf = {0.f, 0.f, 0.f, 0.f};
    #pragma unroll
    for (int r = 0; r < 2; r++)
        #pragma unroll
        for (int c = 0; c < 4; c++) acc[r][c] = zf;

    bf16x8 aA0, aA1, aB0, aB1, bA[4], bB[4];

    aA0 = *(const bf16x8*)(aPtr0);
    aA1 = *(const bf16x8*)(aPtr1);
    bA[0] = *(const bf16x8*)(bBase);
    bA[1] = *(const bf16x8*)(bBase + 512);
    bA[2] = *(const bf16x8*)(bBase + 1024);
    bA[3] = *(const bf16x8*)(bBase + 1536);

    for (int kt = 0; kt < KT1; kt += 2) {
        {   // prefetch odd step
            const unsigned short* bp = bBase + ((size_t)(kt + 1) << 12);
            aB0 = *(const bf16x8*)(aPtr0 + (kt + 1) * 32);
            aB1 = *(const bf16x8*)(aPtr1 + (kt + 1) * 32);
            bB[0] = *(const bf16x8*)(bp);
            bB[1] = *(const bf16x8*)(bp + 512);
            bB[2] = *(const bf16x8*)(bp + 1024);
            bB[3] = *(const bf16x8*)(bp + 1536);
        }
        MM8(aA0, aA1, bA);
        if (kt + 2 < KT1) {   // prefetch next even step
            const unsigned short* bp = bBase + ((size_t)(kt + 2) << 12);
            aA0 = *(const bf16x8*)(aPtr0 + (kt + 2) * 32);
            aA1 = *(const bf16x8*)(aPtr1 + (kt + 2) * 32);
            bA[0] = *(const bf16x8*)(bp);
            bA[1] = *(const bf16x8*)(bp + 512);
            bA[2] = *(const bf16x8*)(bp + 1024);
            bA[3] = *(const bf16x8*)(bp + 1536);
        }
        MM8(aB0, aB1, bB);
    }

    // C/D: col = l16, row = quad*4 + q. Write raw bf16 + gelu'd bf16 (grouped rows).
    const int n0 = nt * 128;
    #pragma unroll
    for (int r = 0; r < 2; r++)
        #pragma unroll
        for (int q = 0; q < 4; q++) {
            int pp = rowStart + wrow + r * 16 + quad * 4 + q;
            if (pp < rowEnd) {
                unsigned short* ep = e1g + (size_t)pp * D_OUT + n0 + wcol + l16;
                unsigned short* gp = g1g + (size_t)pp * D_OUT + n0 + wcol + l16;
                #pragma unroll
                for (int c = 0; c < 4; c++) {
                    unsigned short vb = f2b(acc[r][c][q]);
                    ep[c * 16] = vb;
                    float v = b2f(vb);
                    gp[c * 16] = f2b(v / (1.0f + __expf(-1.702f * v)));
                }
            }
        }
}

// ---------------- GEMM2: out0[idx[p]][n] = f32( g1g @ W2 + e1g ), LDS-free ----------------
__global__ __launch_bounds__(256)
void k5_gemm2(const unsigned short* __restrict__ g1g, const unsigned short* __restrict__ e1g,
              const unsigned short* __restrict__ W2t,
              const int* __restrict__ offs, const int* __restrict__ idx,
              float* __restrict__ out0) {
    const int e = blockIdx.z;
    const int rowStart = offs[e] + blockIdx.y * 64;
    const int rowEnd = offs[e + 1];
    if (rowStart >= rowEnd) return;
    const int nt = blockIdx.x;

    const int tid  = threadIdx.x;
    const int lane = tid & 63;
    const int wave = tid >> 6;
    const int quad = lane >> 4;
    const int l16  = lane & 15;
    const int wrow = (wave & 1) * 32;
    const int wcol = (wave >> 1) * 64;

    int p0 = rowStart + wrow + l16;
    int p1 = p0 + 16;
    const unsigned short* aPtr0 = g1g + (size_t)(p0 < rowEnd ? p0 : rowEnd - 1) * D_OUT + quad * 8;
    const unsigned short* aPtr1 = g1g + (size_t)(p1 < rowEnd ? p1 : rowEnd - 1) * D_OUT + quad * 8;
    const unsigned short* bBase = W2t + ((((size_t)e * 8 + nt) * KT2) << 12) + (wcol + l16) * 32 + quad * 8;

    f32x4 acc[2][4];
    const f32x4 zf = {0.f, 0.f, 0.f, 0.f};
    #pragma unroll
    for (int r = 0; r < 2; r++)
        #pragma unroll
        for (int c = 0; c < 4; c++) acc[r][c] = zf;

    bf16x8 aA0, aA1, aB0, aB1, bA[4], bB[4];

    aA0 = *(const bf16x8*)(aPtr0);
    aA1 = *(const bf16x8*)(aPtr1);
    bA[0] = *(const bf16x8*)(bBase);
    bA[1] = *(const bf16x8*)(bBase + 512);
    bA[2] = *(const bf16x8*)(bBase + 1024);
    bA[3] = *(const bf16x8*)(bBase + 1536);

    for (int kt = 0; kt < KT2; kt += 2) {
        {
            const unsigned short* bp = bBase + ((size_t)(kt + 1) << 12);
            aB0 = *(const bf16x8*)(aPtr0 + (kt + 1) * 32);
            aB1 = *(const bf16x8*)(aPtr1 + (kt + 1) * 32);
            bB[0] = *(const bf16x8*)(bp);
            bB[1] = *(const bf16x8*)(bp + 512);
            bB[2] = *(const bf16x8*)(bp + 1024);
            bB[3] = *(const bf16x8*)(bp + 1536);
        }
        MM8(aA0, aA1, bA);
        if (kt + 2 < KT2) {
            const unsigned short* bp = bBase + ((size_t)(kt + 2) << 12);
            aA0 = *(const bf16x8*)(aPtr0 + (kt + 2) * 32);
            aA1 = *(const bf16x8*)(aPtr1 + (kt + 2) * 32);
            bA[0] = *(const bf16x8*)(bp);
            bA[1] = *(const bf16x8*)(bp + 512);
            bA[2] = *(const bf16x8*)(bp + 1024);
            bA[3] = *(const bf16x8*)(bp + 1536);
        }
        MM8(aB0, aB1, bB);
    }

    // epilogue: s = acc + e1 (residual), scatter f32 to original rows
    const int n0 = nt * 128;
    #pragma unroll
    for (int r = 0; r < 2; r++)
        #pragma unroll
        for (int q = 0; q < 4; q++) {
            int pp = rowStart + wrow + r * 16 + quad * 4 + q;
            if (pp < rowEnd) {
                int orow = idx[pp];
                const unsigned short* ep = e1g + (size_t)pp * D_OUT + n0 + wcol + l16;
                float* op = out0 + (size_t)orow * D_OUT + n0 + wcol + l16;
                #pragma unroll
                for (int c = 0; c < 4; c++)
                    op[c * 16] = acc[r][c][q] + b2f(ep[c * 16]);
            }
        }
}

// ---------------- LN + L2, in place on out0; one wave per row ----------------
__global__ __launch_bounds__(256)
void k4_ln(float* __restrict__ out0, const int* __restrict__ cls,
           const float* __restrict__ gam, const float* __restrict__ bet) {
    const int wave = threadIdx.x >> 6;
    const int lane = threadIdx.x & 63;
    const int b = blockIdx.x * 4 + wave;
    const int e = cls[b];

    float* row = out0 + (size_t)b * D_OUT + lane * 16;
    float v[16];
    #pragma unroll
    for (int j = 0; j < 4; j++) {
        float4 t = *(const float4*)(row + j * 4);
        v[j*4] = t.x; v[j*4+1] = t.y; v[j*4+2] = t.z; v[j*4+3] = t.w;
    }

    float sum = 0.f, sq = 0.f;
    #pragma unroll
    for (int j = 0; j < 16; j++) { sum += v[j]; sq += v[j] * v[j]; }
    #pragma unroll
    for (int o = 32; o; o >>= 1) { sum += __shfl_xor(sum, o, 64); sq += __shfl_xor(sq, o, 64); }
    float mean = sum * (1.0f / 1024.0f);
    float var = sq * (1.0f / 1024.0f) - mean * mean;
    float inv = rsqrtf(var + LN_EPS);

    const float* gp = gam + (size_t)e * D_OUT + lane * 16;
    const float* bp = bet + (size_t)e * D_OUT + lane * 16;
    float y[16]; float y2 = 0.f;
    #pragma unroll
    for (int j = 0; j < 16; j++) {
        y[j] = (v[j] - mean) * inv * gp[j] + bp[j];
        y2 += y[j] * y[j];
    }
    #pragma unroll
    for (int o = 32; o; o >>= 1) y2 += __shfl_xor(y2, o, 64);
    float rn = rsqrtf(y2);

    #pragma unroll
    for (int j = 0; j < 4; j++) {
        float4 t = { y[j*4] * rn, y[j*4+1] * rn, y[j*4+2] * rn, y[j*4+3] * rn };
        *(float4*)(row + j * 4) = t;
    }
}

// ---------------- launch ----------------
extern "C" void kernel_launch(void* const* d_in, const int* in_sizes, int n_in,
                              void* d_out, int out_size, void* d_ws, size_t ws_size,
                              hipStream_t stream) {
    const float* x   = (const float*)d_in[0];
    const float* lg  = (const float*)d_in[1];
    const float* W1  = (const float*)d_in[2];
    const float* W2  = (const float*)d_in[3];
    const float* gam = (const float*)d_in[4];
    const float* bet = (const float*)d_in[5];
    float* out0 = (float*)d_out;
    float* out1 = out0 + (size_t)BSAMP * D_OUT;

    // ws layout: [0,64K) control | [64K, +21M) Wt (W1t then W2t, sequential reuse)
    //            | e1g 8M | g1g 8M | xb 6M.  Total ~45 MB.
    char* ws = (char*)d_ws;
    int* counts = (int*)ws;            // 16
    int* offs   = counts + 16;         // 16
    int* cursor = offs + 16;           // 16
    int* cls    = cursor + 16;         // 4096
    int* idx    = cls + BSAMP;         // 4096
    unsigned short* Wt  = (unsigned short*)(ws + 65536);
    unsigned short* e1g = (unsigned short*)(ws + 65536 + 22020096);
    unsigned short* g1g = e1g + (size_t)BSAMP * D_OUT;
    unsigned short* xb  = g1g + (size_t)BSAMP * D_OUT;

    k4_init<<<1, 64, 0, stream>>>(counts, cursor);
    k4_router<<<16, 256, 0, stream>>>(lg, cls, counts, out1);
    k4_scan<<<1, 64, 0, stream>>>(counts, offs, cursor);
    k4_scatter<<<16, 256, 0, stream>>>(cls, cursor, idx);

    // x -> bf16 once (removes all f2b from gemm1 inner loop)
    k5_xcvt<<<BSAMP * D_IN / (256 * 8), 256, 0, stream>>>(x, xb);

    // W1 -> tiled bf16, then GEMM1 (writes raw e1 and gelu(e1))
    dim3 gc1(D_IN / 32, 4, NEXP);
    k4_cvt<<<gc1, 256, 0, stream>>>(W1, Wt, D_IN);
    dim3 g1(8, 64, NEXP);
    k5_gemm1<<<g1, 256, 0, stream>>>(xb, Wt, offs, idx, e1g, g1g);

    // W2 -> tiled bf16 (reuses Wt region; stream-ordered after gemm1), then GEMM2
    dim3 gc2(D_OUT / 32, 4, NEXP);
    k4_cvt<<<gc2, 256, 0, stream>>>(W2, Wt, D_OUT);
    dim3 g2(8, 64, NEXP);
    k5_gemm2<<<g2, 256, 0, stream>>>(g1g, e1g, Wt, offs, idx, out0);

    k4_ln<<<BSAMP / 4, 256, 0, stream>>>(out0, cls, gam, bet);
}